// Round 11
// baseline (568.118 us; speedup 1.0000x reference)
//
#include <hip/hip_runtime.h>
#include <math.h>

#define DIM 128
#define DIN 20

typedef __attribute__((ext_vector_type(8))) short bf16x8;
typedef __attribute__((ext_vector_type(4))) float f32x4;

__device__ __forceinline__ unsigned short f2bf(float x) {
    unsigned u = __float_as_uint(x);
    u = (u + 0x7FFF + ((u >> 16) & 1)) >> 16;   // RNE
    return (unsigned short)u;
}
__device__ __forceinline__ float sigf(float s) {
    return __builtin_amdgcn_rcpf(1.f + __expf(-s));
}
__device__ __forceinline__ float bflo(unsigned u) { return __uint_as_float(u << 16); }
__device__ __forceinline__ float bfhi(unsigned u) { return __uint_as_float(u & 0xffff0000u); }
__device__ __forceinline__ unsigned packbf(float a, float b) {
    return ((unsigned)f2bf(b) << 16) | f2bf(a);
}
__device__ __forceinline__ float bf2f(short s) {
    return __uint_as_float(((unsigned)(unsigned short)s) << 16);
}

// ---------------------------------------------------------------- CSR build
__global__ void hist_kernel(const int* __restrict__ ei, int* __restrict__ counts, int E) {
    int e = 2 * (blockIdx.x * 256 + threadIdx.x);
    if (e + 1 < E) {
        int2 d = *(const int2*)&ei[E + e];      // row 1 = dst
        atomicAdd(&counts[d.x], 1);
        atomicAdd(&counts[d.y], 1);
    } else if (e < E) {
        atomicAdd(&counts[ei[E + e]], 1);
    }
}

// 4096 elements/block: int4 per thread, register prefix + wave scan + cross-wave LDS.
__global__ __launch_bounds__(1024) void scan1_kernel(const int4* __restrict__ counts4,
                                                     int* __restrict__ incl,
                                                     int* __restrict__ blockSums, int N4) {
    __shared__ int wsum[16];
    int t = threadIdx.x;
    int i4 = blockIdx.x * 1024 + t;
    int4 v = make_int4(0, 0, 0, 0);
    if (i4 < N4) v = counts4[i4];
    int s1 = v.x + v.y, s2 = s1 + v.z, s3 = s2 + v.w;
    int lane = t & 63, w = t >> 6;
    int iw = s3;
    #pragma unroll
    for (int off = 1; off < 64; off <<= 1) {
        int n = __shfl_up(iw, off);
        if (lane >= off) iw += n;
    }
    if (lane == 63) wsum[w] = iw;
    __syncthreads();
    if (t < 16) {
        int x = wsum[t];
        #pragma unroll
        for (int off = 1; off < 16; off <<= 1) {
            int n = __shfl_up(x, off);
            if (t >= off) x += n;
        }
        wsum[t] = x;    // inclusive wave sums
    }
    __syncthreads();
    int base = ((w > 0) ? wsum[w - 1] : 0) + iw - s3;   // exclusive prefix of elem 0
    if (i4 < N4)
        *(int4*)&incl[4 * i4] = make_int4(base + v.x, base + s1, base + s2, base + s3);
    if (t == 0) blockSums[blockIdx.x] = wsum[15];
}

// incl -> exclusive (in place) + cursor copy; block offset recomputed from blockSums.
__global__ __launch_bounds__(1024) void scan3_kernel(const int4* __restrict__ counts4,
                                                     int* __restrict__ rp,
                                                     int* __restrict__ cursor,
                                                     const int* __restrict__ blockSums,
                                                     int G, int N4, int N, int E) {
    __shared__ int boff_s;
    int t = threadIdx.x;
    if (t < 64) {
        int v = (t < G && t < (int)blockIdx.x) ? blockSums[t] : 0;
        #pragma unroll
        for (int off = 32; off; off >>= 1) v += __shfl_xor(v, off);
        if (t == 0) boff_s = v;
    }
    __syncthreads();
    int i4 = blockIdx.x * 1024 + t;
    if (i4 < N4) {
        int4 c = counts4[i4];
        int4 inc = *(const int4*)&rp[4 * i4];
        int b = boff_s;
        int4 ex = make_int4(inc.x - c.x + b, inc.y - c.y + b, inc.z - c.z + b, inc.w - c.w + b);
        *(int4*)&rp[4 * i4] = ex;
        *(int4*)&cursor[4 * i4] = ex;
    }
    if (i4 == 0) rp[N] = E;
}

__global__ void fill_kernel(const int* __restrict__ ei, int* __restrict__ cursor,
                            int* __restrict__ srcS, int E) {
    int e = 2 * (blockIdx.x * 256 + threadIdx.x);
    if (e + 1 < E) {
        int2 s = *(const int2*)&ei[e];           // row 0 = src
        int2 d = *(const int2*)&ei[E + e];       // row 1 = dst
        int p0 = atomicAdd(&cursor[d.x], 1);
        srcS[p0] = s.x;
        int p1 = atomicAdd(&cursor[d.y], 1);
        srcS[p1] = s.y;
    } else if (e < E) {
        int d = ei[E + e];
        int pos = atomicAdd(&cursor[d], 1);
        srcS[pos] = ei[e];
    }
}

// ---------------------------------------------------------------- weight convert
// blocks 0-7: layer weights W[k][c] -> Wt[c][k] bf16 [128][128]
// block  8  : pre_w [20][128]      -> Wtp[c][k] bf16 [128][32], k>=20 zero-padded
__global__ __launch_bounds__(128) void wconv_kernel(const float* __restrict__ wk,
                                                    const float* __restrict__ wq,
                                                    const float* __restrict__ wv,
                                                    const float* __restrict__ ws,
                                                    const float* __restrict__ pw,
                                                    unsigned short* __restrict__ wt,
                                                    unsigned short* __restrict__ wtp) {
    int b = blockIdx.x;
    int c = threadIdx.x;
    if (b < 8) {
        int l = b >> 2, w = b & 3;
        const float* src = (w == 0 ? wk : w == 1 ? wq : w == 2 ? wv : ws) + (size_t)l * DIM * DIM;
        unsigned short* dst = wt + (size_t)b * DIM * DIM;
        for (int k = 0; k < DIM; ++k) dst[c * DIM + k] = f2bf(src[k * DIM + c]);
    } else {
        for (int k = 0; k < 32; ++k)
            wtp[c * 32 + k] = (k < DIN) ? f2bf(pw[k * DIM + c]) : (unsigned short)0;
    }
}

// ---------------------------------------------------------------- pre GEMM via MFMA (K=20 padded to 32)
// 64-row tile, 512 threads = 8 waves; wave w covers cols w*16..w*16+15.
// Stage x f32 coalesced -> bf16 swizzled LDS [64][32]; 4 MFMA/wave; epilogue
// writes bf16 pairs + in-register column stats (zero-pad rows contribute 0).
#define PBM 64
__global__ __launch_bounds__(512) void pre_mfma_kernel(
        const float* __restrict__ x,             // [N][20]
        const unsigned short* __restrict__ Wp,   // [128][32] bf16 (col-major k, padded)
        unsigned int* __restrict__ hb,           // [N][64] bf16 pairs (== [N][128] ushort)
        float* __restrict__ stats, int N) {
    __shared__ float xs[PBM * DIN];              // 5 KB raw f32 tile
    __shared__ unsigned short Asw[PBM * 32];     // 4 KB bf16, swizzled
    int tid = threadIdx.x;
    int row0 = blockIdx.x * PBM;
    int base = row0 * DIN;
    int total = N * DIN;

    if (tid < 320) {                             // 64 rows x 20 f32 = 320 float4, coalesced
        float4 v = make_float4(0.f, 0.f, 0.f, 0.f);
        int gi = base + tid * 4;
        if (gi + 3 < total) {
            v = *(const float4*)(x + gi);
        } else {
            float* vp = (float*)&v;
            #pragma unroll
            for (int j = 0; j < 4; ++j) if (gi + j < total) vp[j] = x[gi + j];
        }
        *(float4*)&xs[tid * 4] = v;
    }
    __syncthreads();

    {   // convert: thread t -> row = t>>3, k4 = (t&7)*4 (zeros for k>=20)
        int r = tid >> 3, k4 = (tid & 7) * 4;
        float v0 = 0.f, v1 = 0.f, v2 = 0.f, v3 = 0.f;
        if (k4 < DIN) {
            float4 f = *(const float4*)&xs[r * DIN + k4];
            v0 = f.x; v1 = f.y; v2 = f.z; v3 = f.w;
        }
        int byteoff = r * 64 + ((k4 * 2) ^ ((r & 3) << 4));
        *(uint2*)((char*)Asw + byteoff) = make_uint2(packbf(v0, v1), packbf(v2, v3));
    }
    __syncthreads();

    int w = tid >> 6, l = tid & 63;
    int c0 = w * 16;
    int lj = l & 15, lg = l >> 4;

    bf16x8 wf = *(const bf16x8*)(Wp + (size_t)(c0 + lj) * 32 + lg * 8);
    f32x4 acc[4];
    #pragma unroll
    for (int mf = 0; mf < 4; ++mf) {
        int r = mf * 16 + lj;
        int off = r * 64 + ((lg * 16) ^ ((r & 3) << 4));
        bf16x8 act = *(const bf16x8*)((char*)Asw + off);
        f32x4 z = {0.f, 0.f, 0.f, 0.f};
        acc[mf] = __builtin_amdgcn_mfma_f32_16x16x32_bf16(wf, act, z, 0, 0, 0);
    }

    // epilogue: lane holds row = row0+mf*16+lj, cols = c0+lg*4+(0..3)
    float s[4] = {}, q[4] = {};
    #pragma unroll
    for (int mf = 0; mf < 4; ++mf) {
        int row = row0 + mf * 16 + lj;
        f32x4 v = acc[mf];
        #pragma unroll
        for (int j = 0; j < 4; ++j) {
            s[j] += v[j];
            q[j] = fmaf(v[j], v[j], q[j]);
        }
        if (row < N) {
            int pidx = (c0 >> 1) + lg * 2;
            *(uint2*)(hb + (size_t)row * 64 + pidx) =
                make_uint2(packbf(v[0], v[1]), packbf(v[2], v[3]));
        }
    }
    #pragma unroll
    for (int off = 1; off < 16; off <<= 1) {     // reduce over lj (16-lane groups)
        #pragma unroll
        for (int j = 0; j < 4; ++j) {
            s[j] += __shfl_xor(s[j], off);
            q[j] += __shfl_xor(q[j], off);
        }
    }
    if (lj == 0) {
        int c = c0 + lg * 4;
        #pragma unroll
        for (int j = 0; j < 4; ++j) {
            atomicAdd(&stats[c + j], s[j]);
            atomicAdd(&stats[128 + c + j], q[j]);
        }
    }
}

// ---------------------------------------------------------------- fused MFMA GEMM: BN+ReLU+L2norm in staging
#define GBM 64
__global__ __launch_bounds__(512) void gemm_fused_kernel(
        const unsigned short* __restrict__ hb,   // [N][128] bf16 (raw, pre-BN)
        const float* __restrict__ stats,         // [256] col sum | sumsq
        const float* __restrict__ gamma, const float* __restrict__ beta,
        const unsigned short* __restrict__ Wt,   // [4][128][128] bf16 (col-major k)
        unsigned int* __restrict__ Kb,           // [N][64] bf16 pairs
        unsigned int* __restrict__ QV,           // [N][128] interleaved Q/V bf16 pairs
        unsigned int* __restrict__ Sb,           // [N][64] bf16 pairs
        float invN, int N) {
    __shared__ unsigned short Asw[GBM * DIM];    // 16 KB, swizzled
    __shared__ float sc_s[DIM], sh_s[DIM];
    int tid = threadIdx.x;
    if (tid < DIM) {
        float s = stats[tid], q = stats[128 + tid];
        float mu = s * invN;
        float var = q * invN - mu * mu;
        float sc = gamma[tid] * rsqrtf(var + 1e-5f);
        sc_s[tid] = sc;
        sh_s[tid] = beta[tid] - mu * sc;
    }
    __syncthreads();
    int row0 = blockIdx.x * GBM;

    #pragma unroll
    for (int i = 0; i < 2; ++i) {
        int g = tid + i * 512;                   // 0..1023
        int r = g >> 4, ch = g & 15;             // row 0..63, 16 lanes per row
        int row = row0 + r;
        int cb = ch * 8;
        float y[8];
        if (row < N) {
            bf16x8 hv = *(const bf16x8*)(hb + (size_t)row * DIM + cb);
            #pragma unroll
            for (int j = 0; j < 8; ++j)
                y[j] = fmaxf(fmaf(bf2f(hv[j]), sc_s[cb + j], sh_s[cb + j]), 0.f);
        } else {
            #pragma unroll
            for (int j = 0; j < 8; ++j) y[j] = 0.f;
        }
        float ss = 0.f;
        #pragma unroll
        for (int j = 0; j < 8; ++j) ss = fmaf(y[j], y[j], ss);
        #pragma unroll
        for (int off = 1; off < 16; off <<= 1) ss += __shfl_xor(ss, off);
        float inv = 1.0f / fmaxf(sqrtf(ss), 1e-12f);
        bf16x8 o;
        #pragma unroll
        for (int j = 0; j < 8; ++j) o[j] = (short)f2bf(y[j] * inv);
        int dst = r * 256 + ((ch * 16) ^ ((r & 7) << 4));
        *(bf16x8*)((char*)Asw + dst) = o;
    }
    __syncthreads();

    int w = tid >> 6, l = tid & 63;
    int c0 = w * 16;
    int lj = l & 15, lg = l >> 4;

    bf16x8 act[4][4];
    #pragma unroll
    for (int mf = 0; mf < 4; ++mf) {
        int r = mf * 16 + lj;
        #pragma unroll
        for (int ks = 0; ks < 4; ++ks) {
            int off = r * 256 + ((ks * 64 + lg * 16) ^ ((r & 7) << 4));
            act[mf][ks] = *(const bf16x8*)((char*)Asw + off);
        }
    }

    #pragma unroll
    for (int wgt = 0; wgt < 4; ++wgt) {          // 0:K 1:Q 2:V 3:S
        const unsigned short* W = Wt + (size_t)wgt * DIM * DIM;
        bf16x8 wf[4];
        #pragma unroll
        for (int ks = 0; ks < 4; ++ks)
            wf[ks] = *(const bf16x8*)(W + (size_t)(c0 + lj) * DIM + ks * 32 + lg * 8);
        f32x4 acc[4] = {};
        #pragma unroll
        for (int mf = 0; mf < 4; ++mf)
            #pragma unroll
            for (int ks = 0; ks < 4; ++ks)
                acc[mf] = __builtin_amdgcn_mfma_f32_16x16x32_bf16(
                    wf[ks], act[mf][ks], acc[mf], 0, 0, 0);
        // lane holds: row = row0 + mf*16 + lj ; cols = c0 + lg*4 + (0..3)
        #pragma unroll
        for (int mf = 0; mf < 4; ++mf) {
            int row = row0 + mf * 16 + lj;
            if (row < N) {
                int col = c0 + lg * 4;
                f32x4 v = acc[mf];
                unsigned p0 = packbf(v[0], v[1]);
                unsigned p1 = packbf(v[2], v[3]);
                if (wgt == 0) {
                    *(uint2*)(Kb + (size_t)row * 64 + (col >> 1)) = make_uint2(p0, p1);
                } else if (wgt == 3) {
                    *(uint2*)(Sb + (size_t)row * 64 + (col >> 1)) = make_uint2(p0, p1);
                } else {
                    unsigned* U = QV + (size_t)row * 128;
                    if (wgt == 1) { U[col]     = p0; U[col + 2] = p1; }
                    else          { U[col + 1] = p0; U[col + 3] = p1; }
                }
            }
        }
    }
}

// ---------------------------------------------------------------- pull aggregation (CSR by dst), bf16 out
__global__ __launch_bounds__(256) void aggregate_kernel(
        const unsigned int* __restrict__ Kb, const unsigned int* __restrict__ QV,
        const unsigned int* __restrict__ Sb,
        const int* __restrict__ rp, const int* __restrict__ srcS,
        unsigned int* __restrict__ outb, int N) {
    int node = blockIdx.x * 4 + (threadIdx.x >> 6);
    if (node >= N) return;
    int l = threadIdx.x & 63;
    int sub = l & 31;
    int half = l >> 5;
    uint2 kp = *(const uint2*)(Kb + (size_t)node * 64 + 2 * sub);
    float k0 = bflo(kp.x), k1 = bfhi(kp.x), k2 = bflo(kp.y), k3 = bfhi(kp.y);
    int beg = rp[node], end = rp[node + 1];
    int cnt = end - beg;
    int npairs = cnt >> 1;
    float a0 = 0, a1 = 0, a2 = 0, a3 = 0;
    int p = 0;
    for (; p + 4 <= npairs; p += 4) {            // 8 edges/iter (4 per half)
        int e = beg + 2 * p + half;
        int j0 = srcS[e];
        int j1 = srcS[e + 2];
        int j2 = srcS[e + 4];
        int j3 = srcS[e + 6];
        uint4 u0 = *(const uint4*)(QV + (size_t)j0 * 128 + 4 * sub);
        uint4 u1 = *(const uint4*)(QV + (size_t)j1 * 128 + 4 * sub);
        uint4 u2 = *(const uint4*)(QV + (size_t)j2 * 128 + 4 * sub);
        uint4 u3 = *(const uint4*)(QV + (size_t)j3 * 128 + 4 * sub);
        a0 = fmaf(sigf(k0 + bflo(u0.x)), bflo(u0.y), a0);
        a1 = fmaf(sigf(k1 + bfhi(u0.x)), bfhi(u0.y), a1);
        a2 = fmaf(sigf(k2 + bflo(u0.z)), bflo(u0.w), a2);
        a3 = fmaf(sigf(k3 + bfhi(u0.z)), bfhi(u0.w), a3);
        a0 = fmaf(sigf(k0 + bflo(u1.x)), bflo(u1.y), a0);
        a1 = fmaf(sigf(k1 + bfhi(u1.x)), bfhi(u1.y), a1);
        a2 = fmaf(sigf(k2 + bflo(u1.z)), bflo(u1.w), a2);
        a3 = fmaf(sigf(k3 + bfhi(u1.z)), bfhi(u1.w), a3);
        a0 = fmaf(sigf(k0 + bflo(u2.x)), bflo(u2.y), a0);
        a1 = fmaf(sigf(k1 + bfhi(u2.x)), bfhi(u2.y), a1);
        a2 = fmaf(sigf(k2 + bflo(u2.z)), bflo(u2.w), a2);
        a3 = fmaf(sigf(k3 + bfhi(u2.z)), bfhi(u2.w), a3);
        a0 = fmaf(sigf(k0 + bflo(u3.x)), bflo(u3.y), a0);
        a1 = fmaf(sigf(k1 + bfhi(u3.x)), bfhi(u3.y), a1);
        a2 = fmaf(sigf(k2 + bflo(u3.z)), bflo(u3.w), a2);
        a3 = fmaf(sigf(k3 + bfhi(u3.z)), bfhi(u3.w), a3);
    }
    for (; p < npairs; ++p) {
        int e = beg + 2 * p + half;
        int j = srcS[e];
        uint4 u = *(const uint4*)(QV + (size_t)j * 128 + 4 * sub);
        a0 = fmaf(sigf(k0 + bflo(u.x)), bflo(u.y), a0);
        a1 = fmaf(sigf(k1 + bfhi(u.x)), bfhi(u.y), a1);
        a2 = fmaf(sigf(k2 + bflo(u.z)), bflo(u.w), a2);
        a3 = fmaf(sigf(k3 + bfhi(u.z)), bfhi(u.w), a3);
    }
    if ((cnt & 1) && half == 0) {                // leftover edge -> half 0
        int j = srcS[beg + cnt - 1];
        uint4 u = *(const uint4*)(QV + (size_t)j * 128 + 4 * sub);
        a0 = fmaf(sigf(k0 + bflo(u.x)), bflo(u.y), a0);
        a1 = fmaf(sigf(k1 + bfhi(u.x)), bfhi(u.y), a1);
        a2 = fmaf(sigf(k2 + bflo(u.z)), bflo(u.w), a2);
        a3 = fmaf(sigf(k3 + bfhi(u.z)), bfhi(u.w), a3);
    }
    a0 += __shfl_xor(a0, 32);
    a1 += __shfl_xor(a1, 32);
    a2 += __shfl_xor(a2, 32);
    a3 += __shfl_xor(a3, 32);
    if (half == 0) {
        uint2 sp = *(const uint2*)(Sb + (size_t)node * 64 + 2 * sub);
        float o0 = a0 + bflo(sp.x);
        float o1 = a1 + bfhi(sp.x);
        float o2 = a2 + bflo(sp.y);
        float o3 = a3 + bfhi(sp.y);
        *(uint2*)(outb + (size_t)node * 64 + 2 * sub) =
            make_uint2(packbf(o0, o1), packbf(o2, o3));
    }
}

// ---------------------------------------------------------------- BN column stats over bf16 pairs [N][64]
// 256 thr = 4 row-group waves (balanced -> barrier safe); LDS reduce; 256 atomics/block.
__global__ __launch_bounds__(256) void colstats_kernel(const unsigned int* __restrict__ hb,
                                                       float* __restrict__ stats, int N) {
    __shared__ float red[1024];
    int tid = threadIdx.x;
    int c = tid & 63;
    int g = tid >> 6;
    float s0 = 0.f, s1 = 0.f, q0 = 0.f, q1 = 0.f;
    for (int r = blockIdx.x * 4 + g; r < N; r += gridDim.x * 4) {
        unsigned p = hb[(size_t)r * 64 + c];
        float a = bflo(p), b = bfhi(p);
        s0 += a; q0 = fmaf(a, a, q0);
        s1 += b; q1 = fmaf(b, b, q1);
    }
    red[tid] = s0; red[256 + tid] = s1; red[512 + tid] = q0; red[768 + tid] = q1;
    __syncthreads();
    if (tid < 64) {
        float S0 = red[c] + red[c + 64] + red[c + 128] + red[c + 192];
        float S1 = red[256 + c] + red[256 + c + 64] + red[256 + c + 128] + red[256 + c + 192];
        float Q0 = red[512 + c] + red[512 + c + 64] + red[512 + c + 128] + red[512 + c + 192];
        float Q1 = red[768 + c] + red[768 + c + 64] + red[768 + c + 128] + red[768 + c + 192];
        atomicAdd(&stats[2 * c], S0);
        atomicAdd(&stats[2 * c + 1], S1);
        atomicAdd(&stats[128 + 2 * c], Q0);
        atomicAdd(&stats[128 + 2 * c + 1], Q1);
    }
}

// ---------------------------------------------------------------- final BN + ReLU + L2 norm: bf16 in -> f32 out
__global__ __launch_bounds__(256) void finalize_kernel(
        const unsigned int* __restrict__ hb, float* __restrict__ out,
        const float* __restrict__ stats,
        const float* __restrict__ gamma, const float* __restrict__ beta,
        float invN, int N) {
    __shared__ float sc_s[DIM], sh_s[DIM];
    int tid = threadIdx.x;
    if (tid < DIM) {
        float s = stats[tid], q = stats[128 + tid];
        float mu = s * invN;
        float var = q * invN - mu * mu;
        float sc = gamma[tid] * rsqrtf(var + 1e-5f);
        sc_s[tid] = sc;
        sh_s[tid] = beta[tid] - mu * sc;
    }
    __syncthreads();
    int row = blockIdx.x * 4 + (tid >> 6);
    int lane = tid & 63;
    if (row >= N) return;
    unsigned p = hb[(size_t)row * 64 + lane];   // cols 2*lane, 2*lane+1
    int c0 = 2 * lane, c1 = 2 * lane + 1;
    float y0 = fmaxf(fmaf(bflo(p), sc_s[c0], sh_s[c0]), 0.f);
    float y1 = fmaxf(fmaf(bfhi(p), sc_s[c1], sh_s[c1]), 0.f);
    float ss = y0 * y0 + y1 * y1;
    #pragma unroll
    for (int off = 32; off; off >>= 1) ss += __shfl_xor(ss, off);
    float inv = 1.0f / fmaxf(sqrtf(ss), 1e-12f);
    *(float2*)(out + (size_t)row * DIM + c0) = make_float2(y0 * inv, y1 * inv);
}

// ---------------------------------------------------------------- launch
extern "C" void kernel_launch(void* const* d_in, const int* in_sizes, int n_in,
                              void* d_out, int out_size, void* d_ws, size_t ws_size,
                              hipStream_t stream) {
    const float* x     = (const float*)d_in[0];
    const int*   ei    = (const int*)d_in[1];
    const float* pre_w = (const float*)d_in[2];
    const float* pre_g = (const float*)d_in[3];
    const float* pre_b = (const float*)d_in[4];
    const float* mp_wk = (const float*)d_in[5];
    const float* mp_wq = (const float*)d_in[6];
    const float* mp_wv = (const float*)d_in[7];
    const float* mp_ws = (const float*)d_in[8];
    const float* mp_g  = (const float*)d_in[9];
    const float* mp_b  = (const float*)d_in[10];
    const int N = in_sizes[0] / DIN;     // 50000
    const int E = in_sizes[1] / 2;       // 800000
    const int N4 = (N + 3) / 4;

    char* wsp = (char*)d_ws;
    size_t off = 0;
    auto alloc = [&](size_t bytes) {
        void* p = wsp + off;
        off = (off + bytes + 255) & ~(size_t)255;
        return p;
    };
    unsigned short* hAb  = (unsigned short*)alloc((size_t)N * DIM * 2);  // raw pre-GEMM out
    unsigned int*   hBb  = (unsigned int*)alloc((size_t)N * 64 * 4);     // agg out l0 (bf16 pairs)
    unsigned int*   hCb  = (unsigned int*)alloc((size_t)N * 64 * 4);     // agg out l1 (bf16 pairs)
    unsigned int*   Kb   = (unsigned int*)alloc((size_t)N * 64 * 4);
    unsigned int*   QVb  = (unsigned int*)alloc((size_t)N * 128 * 4);    // interleaved Q/V bf16 pairs
    unsigned int*   Sb   = (unsigned int*)alloc((size_t)N * 64 * 4);
    unsigned short* wt   = (unsigned short*)alloc((size_t)8 * DIM * DIM * 2);
    unsigned short* wtp  = (unsigned short*)alloc((size_t)DIM * 32 * 2);
    // zero region: counts (padded to x4) + stats0/1/2 (contiguous, one memset)
    int*   counts = (int*)alloc((size_t)N4 * 16);
    float* stats0 = (float*)alloc(256 * 4);
    float* stats1 = (float*)alloc(256 * 4);
    float* stats2 = (float*)alloc(256 * 4);
    size_t zero_bytes = (size_t)((char*)stats2 + 256 * 4 - (char*)counts);
    int*   rp     = (int*)alloc((size_t)(N4 * 4 + 1) * 4);
    int*   cursor = (int*)alloc((size_t)N4 * 16);
    int*   bsums  = (int*)alloc(256);
    int*   srcS   = (int*)alloc((size_t)E * 4);

    hipMemsetAsync(counts, 0, zero_bytes, stream);

    // --- CSR by dst (same edges both layers → build once per call)
    hist_kernel<<<(E / 2 + 255) / 256, 256, 0, stream>>>(ei, counts, E);
    int G1 = (N4 + 1023) / 1024;
    scan1_kernel<<<G1, 1024, 0, stream>>>((const int4*)counts, rp, bsums, N4);
    scan3_kernel<<<G1, 1024, 0, stream>>>((const int4*)counts, rp, cursor, bsums, G1, N4, N, E);
    fill_kernel<<<(E / 2 + 255) / 256, 256, 0, stream>>>(ei, cursor, srcS, E);

    // --- weights -> bf16 transposed (+ padded pre_w)
    wconv_kernel<<<9, 128, 0, stream>>>(mp_wk, mp_wq, mp_wv, mp_ws, pre_w, wt, wtp);

    // --- pre layer: MFMA Linear (bf16 out) + fused stats
    pre_mfma_kernel<<<(N + PBM - 1) / PBM, 512, 0, stream>>>(
        x, wtp, (unsigned int*)hAb, stats0, N);

    float invN = 1.0f / N;
    int gemm_blocks = (N + GBM - 1) / GBM;

    // --- layer 0
    gemm_fused_kernel<<<gemm_blocks, 512, 0, stream>>>(
        hAb, stats0, pre_g, pre_b, wt, Kb, QVb, Sb, invN, N);
    aggregate_kernel<<<(N + 3) / 4, 256, 0, stream>>>(Kb, QVb, Sb, rp, srcS, hBb, N);
    colstats_kernel<<<1024, 256, 0, stream>>>(hBb, stats1, N);

    // --- layer 1
    gemm_fused_kernel<<<gemm_blocks, 512, 0, stream>>>(
        (const unsigned short*)hBb, stats1, mp_g, mp_b,
        wt + (size_t)4 * DIM * DIM, Kb, QVb, Sb, invN, N);
    aggregate_kernel<<<(N + 3) / 4, 256, 0, stream>>>(Kb, QVb, Sb, rp, srcS, hCb, N);
    colstats_kernel<<<1024, 256, 0, stream>>>(hCb, stats2, N);
    finalize_kernel<<<(N + 3) / 4, 256, 0, stream>>>(
        hCb, (float*)d_out, stats2, mp_g + DIM, mp_b + DIM, invN, N);
}

// Round 12
// 412.391 us; speedup vs baseline: 1.3776x; 1.3776x over previous
//
#include <hip/hip_runtime.h>
#include <math.h>

#define DIM 128
#define DIN 20
#define NPART 32   // stats partials (contention killer)

typedef __attribute__((ext_vector_type(8))) short bf16x8;
typedef __attribute__((ext_vector_type(4))) float f32x4;

__device__ __forceinline__ unsigned short f2bf(float x) {
    unsigned u = __float_as_uint(x);
    u = (u + 0x7FFF + ((u >> 16) & 1)) >> 16;   // RNE
    return (unsigned short)u;
}
__device__ __forceinline__ float sigf(float s) {
    return __builtin_amdgcn_rcpf(1.f + __expf(-s));
}
__device__ __forceinline__ float bflo(unsigned u) { return __uint_as_float(u << 16); }
__device__ __forceinline__ float bfhi(unsigned u) { return __uint_as_float(u & 0xffff0000u); }
__device__ __forceinline__ unsigned packbf(float a, float b) {
    return ((unsigned)f2bf(b) << 16) | f2bf(a);
}
__device__ __forceinline__ float bf2f(short s) {
    return __uint_as_float(((unsigned)(unsigned short)s) << 16);
}

// ---------------------------------------------------------------- CSR build
__global__ void hist_kernel(const int* __restrict__ ei, int* __restrict__ counts, int E) {
    int e = 2 * (blockIdx.x * 256 + threadIdx.x);
    if (e + 1 < E) {
        int2 d = *(const int2*)&ei[E + e];      // row 1 = dst
        atomicAdd(&counts[d.x], 1);
        atomicAdd(&counts[d.y], 1);
    } else if (e < E) {
        atomicAdd(&counts[ei[E + e]], 1);
    }
}

// 4096 elements/block: int4 per thread, register prefix + wave scan + cross-wave LDS.
__global__ __launch_bounds__(1024) void scan1_kernel(const int4* __restrict__ counts4,
                                                     int* __restrict__ incl,
                                                     int* __restrict__ blockSums, int N4) {
    __shared__ int wsum[16];
    int t = threadIdx.x;
    int i4 = blockIdx.x * 1024 + t;
    int4 v = make_int4(0, 0, 0, 0);
    if (i4 < N4) v = counts4[i4];
    int s1 = v.x + v.y, s2 = s1 + v.z, s3 = s2 + v.w;
    int lane = t & 63, w = t >> 6;
    int iw = s3;
    #pragma unroll
    for (int off = 1; off < 64; off <<= 1) {
        int n = __shfl_up(iw, off);
        if (lane >= off) iw += n;
    }
    if (lane == 63) wsum[w] = iw;
    __syncthreads();
    if (t < 16) {
        int x = wsum[t];
        #pragma unroll
        for (int off = 1; off < 16; off <<= 1) {
            int n = __shfl_up(x, off);
            if (t >= off) x += n;
        }
        wsum[t] = x;    // inclusive wave sums
    }
    __syncthreads();
    int base = ((w > 0) ? wsum[w - 1] : 0) + iw - s3;   // exclusive prefix of elem 0
    if (i4 < N4)
        *(int4*)&incl[4 * i4] = make_int4(base + v.x, base + s1, base + s2, base + s3);
    if (t == 0) blockSums[blockIdx.x] = wsum[15];
}

// incl -> exclusive (in place) + cursor copy; block offset recomputed from blockSums.
__global__ __launch_bounds__(1024) void scan3_kernel(const int4* __restrict__ counts4,
                                                     int* __restrict__ rp,
                                                     int* __restrict__ cursor,
                                                     const int* __restrict__ blockSums,
                                                     int G, int N4, int N, int E) {
    __shared__ int boff_s;
    int t = threadIdx.x;
    if (t < 64) {
        int v = (t < G && t < (int)blockIdx.x) ? blockSums[t] : 0;
        #pragma unroll
        for (int off = 32; off; off >>= 1) v += __shfl_xor(v, off);
        if (t == 0) boff_s = v;
    }
    __syncthreads();
    int i4 = blockIdx.x * 1024 + t;
    if (i4 < N4) {
        int4 c = counts4[i4];
        int4 inc = *(const int4*)&rp[4 * i4];
        int b = boff_s;
        int4 ex = make_int4(inc.x - c.x + b, inc.y - c.y + b, inc.z - c.z + b, inc.w - c.w + b);
        *(int4*)&rp[4 * i4] = ex;
        *(int4*)&cursor[4 * i4] = ex;
    }
    if (i4 == 0) rp[N] = E;
}

__global__ void fill_kernel(const int* __restrict__ ei, int* __restrict__ cursor,
                            int* __restrict__ srcS, int E) {
    int e = 2 * (blockIdx.x * 256 + threadIdx.x);
    if (e + 1 < E) {
        int2 s = *(const int2*)&ei[e];           // row 0 = src
        int2 d = *(const int2*)&ei[E + e];       // row 1 = dst
        int p0 = atomicAdd(&cursor[d.x], 1);
        srcS[p0] = s.x;
        int p1 = atomicAdd(&cursor[d.y], 1);
        srcS[p1] = s.y;
    } else if (e < E) {
        int d = ei[E + e];
        int pos = atomicAdd(&cursor[d], 1);
        srcS[pos] = ei[e];
    }
}

// ---------------------------------------------------------------- weight convert
// blocks 0-7: layer weights W[k][c] -> Wt[c][k] bf16 [128][128]
// block  8  : pre_w [20][128]      -> Wtp[c][k] bf16 [128][32], k>=20 zero-padded
__global__ __launch_bounds__(128) void wconv_kernel(const float* __restrict__ wk,
                                                    const float* __restrict__ wq,
                                                    const float* __restrict__ wv,
                                                    const float* __restrict__ ws,
                                                    const float* __restrict__ pw,
                                                    unsigned short* __restrict__ wt,
                                                    unsigned short* __restrict__ wtp) {
    int b = blockIdx.x;
    int c = threadIdx.x;
    if (b < 8) {
        int l = b >> 2, w = b & 3;
        const float* src = (w == 0 ? wk : w == 1 ? wq : w == 2 ? wv : ws) + (size_t)l * DIM * DIM;
        unsigned short* dst = wt + (size_t)b * DIM * DIM;
        for (int k = 0; k < DIM; ++k) dst[c * DIM + k] = f2bf(src[k * DIM + c]);
    } else {
        for (int k = 0; k < 32; ++k)
            wtp[c * 32 + k] = (k < DIN) ? f2bf(pw[k * DIM + c]) : (unsigned short)0;
    }
}

// ---------------------------------------------------------------- pre GEMM via MFMA (K=20 padded to 32)
// 64-row tile, 512 threads = 8 waves; wave w covers cols w*16..w*16+15.
// Stats go into 32-way partials: stats[(blk&31)*256 + ...].
#define PBM 64
__global__ __launch_bounds__(512) void pre_mfma_kernel(
        const float* __restrict__ x,             // [N][20]
        const unsigned short* __restrict__ Wp,   // [128][32] bf16 (col-major k, padded)
        unsigned int* __restrict__ hb,           // [N][64] bf16 pairs
        float* __restrict__ stats, int N) {      // [32][256] partials
    __shared__ float xs[PBM * DIN];              // 5 KB raw f32 tile
    __shared__ unsigned short Asw[PBM * 32];     // 4 KB bf16, swizzled
    int tid = threadIdx.x;
    int row0 = blockIdx.x * PBM;
    int base = row0 * DIN;
    int total = N * DIN;

    if (tid < 320) {                             // 64 rows x 20 f32 = 320 float4, coalesced
        float4 v = make_float4(0.f, 0.f, 0.f, 0.f);
        int gi = base + tid * 4;
        if (gi + 3 < total) {
            v = *(const float4*)(x + gi);
        } else {
            float* vp = (float*)&v;
            #pragma unroll
            for (int j = 0; j < 4; ++j) if (gi + j < total) vp[j] = x[gi + j];
        }
        *(float4*)&xs[tid * 4] = v;
    }
    __syncthreads();

    {   // convert: thread t -> row = t>>3, k4 = (t&7)*4 (zeros for k>=20)
        int r = tid >> 3, k4 = (tid & 7) * 4;
        float v0 = 0.f, v1 = 0.f, v2 = 0.f, v3 = 0.f;
        if (k4 < DIN) {
            float4 f = *(const float4*)&xs[r * DIN + k4];
            v0 = f.x; v1 = f.y; v2 = f.z; v3 = f.w;
        }
        int byteoff = r * 64 + ((k4 * 2) ^ ((r & 3) << 4));
        *(uint2*)((char*)Asw + byteoff) = make_uint2(packbf(v0, v1), packbf(v2, v3));
    }
    __syncthreads();

    int w = tid >> 6, l = tid & 63;
    int c0 = w * 16;
    int lj = l & 15, lg = l >> 4;

    bf16x8 wf = *(const bf16x8*)(Wp + (size_t)(c0 + lj) * 32 + lg * 8);
    f32x4 acc[4];
    #pragma unroll
    for (int mf = 0; mf < 4; ++mf) {
        int r = mf * 16 + lj;
        int off = r * 64 + ((lg * 16) ^ ((r & 3) << 4));
        bf16x8 act = *(const bf16x8*)((char*)Asw + off);
        f32x4 z = {0.f, 0.f, 0.f, 0.f};
        acc[mf] = __builtin_amdgcn_mfma_f32_16x16x32_bf16(wf, act, z, 0, 0, 0);
    }

    // epilogue: lane holds row = row0+mf*16+lj, cols = c0+lg*4+(0..3)
    float s[4] = {}, q[4] = {};
    #pragma unroll
    for (int mf = 0; mf < 4; ++mf) {
        int row = row0 + mf * 16 + lj;
        f32x4 v = acc[mf];
        #pragma unroll
        for (int j = 0; j < 4; ++j) {
            s[j] += v[j];
            q[j] = fmaf(v[j], v[j], q[j]);
        }
        if (row < N) {
            int pidx = (c0 >> 1) + lg * 2;
            *(uint2*)(hb + (size_t)row * 64 + pidx) =
                make_uint2(packbf(v[0], v[1]), packbf(v[2], v[3]));
        }
    }
    #pragma unroll
    for (int off = 1; off < 16; off <<= 1) {     // reduce over lj (16-lane groups)
        #pragma unroll
        for (int j = 0; j < 4; ++j) {
            s[j] += __shfl_xor(s[j], off);
            q[j] += __shfl_xor(q[j], off);
        }
    }
    if (lj == 0) {
        float* sp = stats + (blockIdx.x & (NPART - 1)) * 256;
        int c = c0 + lg * 4;
        #pragma unroll
        for (int j = 0; j < 4; ++j) {
            atomicAdd(&sp[c + j], s[j]);
            atomicAdd(&sp[128 + c + j], q[j]);
        }
    }
}

// ---------------------------------------------------------------- fused MFMA GEMM: BN+ReLU+L2norm in staging
// Prologue reduces the 32 stats partials -> scale/shift.
#define GBM 64
__global__ __launch_bounds__(512) void gemm_fused_kernel(
        const unsigned short* __restrict__ hb,   // [N][128] bf16 (raw, pre-BN)
        const float* __restrict__ stats,         // [32][256] partials
        const float* __restrict__ gamma, const float* __restrict__ beta,
        const unsigned short* __restrict__ Wt,   // [4][128][128] bf16 (col-major k)
        unsigned int* __restrict__ Kb,           // [N][64] bf16 pairs
        unsigned int* __restrict__ QV,           // [N][128] interleaved Q/V bf16 pairs
        unsigned int* __restrict__ Sb,           // [N][64] bf16 pairs
        float invN, int N) {
    __shared__ unsigned short Asw[GBM * DIM];    // 16 KB, swizzled
    __shared__ float sc_s[DIM], sh_s[DIM];
    int tid = threadIdx.x;
    if (tid < DIM) {
        float s = 0.f, q = 0.f;
        #pragma unroll 8
        for (int p = 0; p < NPART; ++p) {
            s += stats[p * 256 + tid];
            q += stats[p * 256 + 128 + tid];
        }
        float mu = s * invN;
        float var = q * invN - mu * mu;
        float sc = gamma[tid] * rsqrtf(var + 1e-5f);
        sc_s[tid] = sc;
        sh_s[tid] = beta[tid] - mu * sc;
    }
    __syncthreads();
    int row0 = blockIdx.x * GBM;

    #pragma unroll
    for (int i = 0; i < 2; ++i) {
        int g = tid + i * 512;                   // 0..1023
        int r = g >> 4, ch = g & 15;             // row 0..63, 16 lanes per row
        int row = row0 + r;
        int cb = ch * 8;
        float y[8];
        if (row < N) {
            bf16x8 hv = *(const bf16x8*)(hb + (size_t)row * DIM + cb);
            #pragma unroll
            for (int j = 0; j < 8; ++j)
                y[j] = fmaxf(fmaf(bf2f(hv[j]), sc_s[cb + j], sh_s[cb + j]), 0.f);
        } else {
            #pragma unroll
            for (int j = 0; j < 8; ++j) y[j] = 0.f;
        }
        float ss = 0.f;
        #pragma unroll
        for (int j = 0; j < 8; ++j) ss = fmaf(y[j], y[j], ss);
        #pragma unroll
        for (int off = 1; off < 16; off <<= 1) ss += __shfl_xor(ss, off);
        float inv = 1.0f / fmaxf(sqrtf(ss), 1e-12f);
        bf16x8 o;
        #pragma unroll
        for (int j = 0; j < 8; ++j) o[j] = (short)f2bf(y[j] * inv);
        int dst = r * 256 + ((ch * 16) ^ ((r & 7) << 4));
        *(bf16x8*)((char*)Asw + dst) = o;
    }
    __syncthreads();

    int w = tid >> 6, l = tid & 63;
    int c0 = w * 16;
    int lj = l & 15, lg = l >> 4;

    bf16x8 act[4][4];
    #pragma unroll
    for (int mf = 0; mf < 4; ++mf) {
        int r = mf * 16 + lj;
        #pragma unroll
        for (int ks = 0; ks < 4; ++ks) {
            int off = r * 256 + ((ks * 64 + lg * 16) ^ ((r & 7) << 4));
            act[mf][ks] = *(const bf16x8*)((char*)Asw + off);
        }
    }

    #pragma unroll
    for (int wgt = 0; wgt < 4; ++wgt) {          // 0:K 1:Q 2:V 3:S
        const unsigned short* W = Wt + (size_t)wgt * DIM * DIM;
        bf16x8 wf[4];
        #pragma unroll
        for (int ks = 0; ks < 4; ++ks)
            wf[ks] = *(const bf16x8*)(W + (size_t)(c0 + lj) * DIM + ks * 32 + lg * 8);
        f32x4 acc[4] = {};
        #pragma unroll
        for (int mf = 0; mf < 4; ++mf)
            #pragma unroll
            for (int ks = 0; ks < 4; ++ks)
                acc[mf] = __builtin_amdgcn_mfma_f32_16x16x32_bf16(
                    wf[ks], act[mf][ks], acc[mf], 0, 0, 0);
        // lane holds: row = row0 + mf*16 + lj ; cols = c0 + lg*4 + (0..3)
        #pragma unroll
        for (int mf = 0; mf < 4; ++mf) {
            int row = row0 + mf * 16 + lj;
            if (row < N) {
                int col = c0 + lg * 4;
                f32x4 v = acc[mf];
                unsigned p0 = packbf(v[0], v[1]);
                unsigned p1 = packbf(v[2], v[3]);
                if (wgt == 0) {
                    *(uint2*)(Kb + (size_t)row * 64 + (col >> 1)) = make_uint2(p0, p1);
                } else if (wgt == 3) {
                    *(uint2*)(Sb + (size_t)row * 64 + (col >> 1)) = make_uint2(p0, p1);
                } else {
                    unsigned* U = QV + (size_t)row * 128;
                    if (wgt == 1) { U[col]     = p0; U[col + 2] = p1; }
                    else          { U[col + 1] = p0; U[col + 3] = p1; }
                }
            }
        }
    }
}

// ---------------------------------------------------------------- pull aggregation (CSR by dst), bf16 out
__global__ __launch_bounds__(256) void aggregate_kernel(
        const unsigned int* __restrict__ Kb, const unsigned int* __restrict__ QV,
        const unsigned int* __restrict__ Sb,
        const int* __restrict__ rp, const int* __restrict__ srcS,
        unsigned int* __restrict__ outb, int N) {
    int node = blockIdx.x * 4 + (threadIdx.x >> 6);
    if (node >= N) return;
    int l = threadIdx.x & 63;
    int sub = l & 31;
    int half = l >> 5;
    uint2 kp = *(const uint2*)(Kb + (size_t)node * 64 + 2 * sub);
    float k0 = bflo(kp.x), k1 = bfhi(kp.x), k2 = bflo(kp.y), k3 = bfhi(kp.y);
    int beg = rp[node], end = rp[node + 1];
    int cnt = end - beg;
    int npairs = cnt >> 1;
    float a0 = 0, a1 = 0, a2 = 0, a3 = 0;
    int p = 0;
    for (; p + 4 <= npairs; p += 4) {            // 8 edges/iter (4 per half)
        int e = beg + 2 * p + half;
        int j0 = srcS[e];
        int j1 = srcS[e + 2];
        int j2 = srcS[e + 4];
        int j3 = srcS[e + 6];
        uint4 u0 = *(const uint4*)(QV + (size_t)j0 * 128 + 4 * sub);
        uint4 u1 = *(const uint4*)(QV + (size_t)j1 * 128 + 4 * sub);
        uint4 u2 = *(const uint4*)(QV + (size_t)j2 * 128 + 4 * sub);
        uint4 u3 = *(const uint4*)(QV + (size_t)j3 * 128 + 4 * sub);
        a0 = fmaf(sigf(k0 + bflo(u0.x)), bflo(u0.y), a0);
        a1 = fmaf(sigf(k1 + bfhi(u0.x)), bfhi(u0.y), a1);
        a2 = fmaf(sigf(k2 + bflo(u0.z)), bflo(u0.w), a2);
        a3 = fmaf(sigf(k3 + bfhi(u0.z)), bfhi(u0.w), a3);
        a0 = fmaf(sigf(k0 + bflo(u1.x)), bflo(u1.y), a0);
        a1 = fmaf(sigf(k1 + bfhi(u1.x)), bfhi(u1.y), a1);
        a2 = fmaf(sigf(k2 + bflo(u1.z)), bflo(u1.w), a2);
        a3 = fmaf(sigf(k3 + bfhi(u1.z)), bfhi(u1.w), a3);
        a0 = fmaf(sigf(k0 + bflo(u2.x)), bflo(u2.y), a0);
        a1 = fmaf(sigf(k1 + bfhi(u2.x)), bfhi(u2.y), a1);
        a2 = fmaf(sigf(k2 + bflo(u2.z)), bflo(u2.w), a2);
        a3 = fmaf(sigf(k3 + bfhi(u2.z)), bfhi(u2.w), a3);
        a0 = fmaf(sigf(k0 + bflo(u3.x)), bflo(u3.y), a0);
        a1 = fmaf(sigf(k1 + bfhi(u3.x)), bfhi(u3.y), a1);
        a2 = fmaf(sigf(k2 + bflo(u3.z)), bflo(u3.w), a2);
        a3 = fmaf(sigf(k3 + bfhi(u3.z)), bfhi(u3.w), a3);
    }
    for (; p < npairs; ++p) {
        int e = beg + 2 * p + half;
        int j = srcS[e];
        uint4 u = *(const uint4*)(QV + (size_t)j * 128 + 4 * sub);
        a0 = fmaf(sigf(k0 + bflo(u.x)), bflo(u.y), a0);
        a1 = fmaf(sigf(k1 + bfhi(u.x)), bfhi(u.y), a1);
        a2 = fmaf(sigf(k2 + bflo(u.z)), bflo(u.w), a2);
        a3 = fmaf(sigf(k3 + bfhi(u.z)), bfhi(u.w), a3);
    }
    if ((cnt & 1) && half == 0) {                // leftover edge -> half 0
        int j = srcS[beg + cnt - 1];
        uint4 u = *(const uint4*)(QV + (size_t)j * 128 + 4 * sub);
        a0 = fmaf(sigf(k0 + bflo(u.x)), bflo(u.y), a0);
        a1 = fmaf(sigf(k1 + bfhi(u.x)), bfhi(u.y), a1);
        a2 = fmaf(sigf(k2 + bflo(u.z)), bflo(u.w), a2);
        a3 = fmaf(sigf(k3 + bfhi(u.z)), bfhi(u.w), a3);
    }
    a0 += __shfl_xor(a0, 32);
    a1 += __shfl_xor(a1, 32);
    a2 += __shfl_xor(a2, 32);
    a3 += __shfl_xor(a3, 32);
    if (half == 0) {
        uint2 sp = *(const uint2*)(Sb + (size_t)node * 64 + 2 * sub);
        float o0 = a0 + bflo(sp.x);
        float o1 = a1 + bfhi(sp.x);
        float o2 = a2 + bflo(sp.y);
        float o3 = a3 + bfhi(sp.y);
        *(uint2*)(outb + (size_t)node * 64 + 2 * sub) =
            make_uint2(packbf(o0, o1), packbf(o2, o3));
    }
}

// ---------------------------------------------------------------- BN column stats over bf16 pairs [N][64]
// 256 thr = 4 row-group waves; LDS reduce; atomics into 32-way partials.
__global__ __launch_bounds__(256) void colstats_kernel(const unsigned int* __restrict__ hb,
                                                       float* __restrict__ stats, int N) {
    __shared__ float red[1024];
    int tid = threadIdx.x;
    int c = tid & 63;
    int g = tid >> 6;
    float s0 = 0.f, s1 = 0.f, q0 = 0.f, q1 = 0.f;
    for (int r = blockIdx.x * 4 + g; r < N; r += gridDim.x * 4) {
        unsigned p = hb[(size_t)r * 64 + c];
        float a = bflo(p), b = bfhi(p);
        s0 += a; q0 = fmaf(a, a, q0);
        s1 += b; q1 = fmaf(b, b, q1);
    }
    red[tid] = s0; red[256 + tid] = s1; red[512 + tid] = q0; red[768 + tid] = q1;
    __syncthreads();
    if (tid < 64) {
        float* sp = stats + (blockIdx.x & (NPART - 1)) * 256;
        float S0 = red[c] + red[c + 64] + red[c + 128] + red[c + 192];
        float S1 = red[256 + c] + red[256 + c + 64] + red[256 + c + 128] + red[256 + c + 192];
        float Q0 = red[512 + c] + red[512 + c + 64] + red[512 + c + 128] + red[512 + c + 192];
        float Q1 = red[768 + c] + red[768 + c + 64] + red[768 + c + 128] + red[768 + c + 192];
        atomicAdd(&sp[2 * c], S0);
        atomicAdd(&sp[2 * c + 1], S1);
        atomicAdd(&sp[128 + 2 * c], Q0);
        atomicAdd(&sp[128 + 2 * c + 1], Q1);
    }
}

// ---------------------------------------------------------------- final BN + ReLU + L2 norm: bf16 in -> f32 out
__global__ __launch_bounds__(256) void finalize_kernel(
        const unsigned int* __restrict__ hb, float* __restrict__ out,
        const float* __restrict__ stats,     // [32][256] partials
        const float* __restrict__ gamma, const float* __restrict__ beta,
        float invN, int N) {
    __shared__ float sc_s[DIM], sh_s[DIM];
    int tid = threadIdx.x;
    if (tid < DIM) {
        float s = 0.f, q = 0.f;
        #pragma unroll 8
        for (int p = 0; p < NPART; ++p) {
            s += stats[p * 256 + tid];
            q += stats[p * 256 + 128 + tid];
        }
        float mu = s * invN;
        float var = q * invN - mu * mu;
        float sc = gamma[tid] * rsqrtf(var + 1e-5f);
        sc_s[tid] = sc;
        sh_s[tid] = beta[tid] - mu * sc;
    }
    __syncthreads();
    int row = blockIdx.x * 4 + (tid >> 6);
    int lane = tid & 63;
    if (row >= N) return;
    unsigned p = hb[(size_t)row * 64 + lane];   // cols 2*lane, 2*lane+1
    int c0 = 2 * lane, c1 = 2 * lane + 1;
    float y0 = fmaxf(fmaf(bflo(p), sc_s[c0], sh_s[c0]), 0.f);
    float y1 = fmaxf(fmaf(bfhi(p), sc_s[c1], sh_s[c1]), 0.f);
    float ss = y0 * y0 + y1 * y1;
    #pragma unroll
    for (int off = 32; off; off >>= 1) ss += __shfl_xor(ss, off);
    float inv = 1.0f / fmaxf(sqrtf(ss), 1e-12f);
    *(float2*)(out + (size_t)row * DIM + c0) = make_float2(y0 * inv, y1 * inv);
}

// ---------------------------------------------------------------- launch
extern "C" void kernel_launch(void* const* d_in, const int* in_sizes, int n_in,
                              void* d_out, int out_size, void* d_ws, size_t ws_size,
                              hipStream_t stream) {
    const float* x     = (const float*)d_in[0];
    const int*   ei    = (const int*)d_in[1];
    const float* pre_w = (const float*)d_in[2];
    const float* pre_g = (const float*)d_in[3];
    const float* pre_b = (const float*)d_in[4];
    const float* mp_wk = (const float*)d_in[5];
    const float* mp_wq = (const float*)d_in[6];
    const float* mp_wv = (const float*)d_in[7];
    const float* mp_ws = (const float*)d_in[8];
    const float* mp_g  = (const float*)d_in[9];
    const float* mp_b  = (const float*)d_in[10];
    const int N = in_sizes[0] / DIN;     // 50000
    const int E = in_sizes[1] / 2;       // 800000
    const int N4 = (N + 3) / 4;

    char* wsp = (char*)d_ws;
    size_t off = 0;
    auto alloc = [&](size_t bytes) {
        void* p = wsp + off;
        off = (off + bytes + 255) & ~(size_t)255;
        return p;
    };
    unsigned short* hAb  = (unsigned short*)alloc((size_t)N * DIM * 2);  // raw pre-GEMM out
    unsigned int*   hBb  = (unsigned int*)alloc((size_t)N * 64 * 4);     // agg out l0 (bf16 pairs)
    unsigned int*   hCb  = (unsigned int*)alloc((size_t)N * 64 * 4);     // agg out l1 (bf16 pairs)
    unsigned int*   Kb   = (unsigned int*)alloc((size_t)N * 64 * 4);
    unsigned int*   QVb  = (unsigned int*)alloc((size_t)N * 128 * 4);    // interleaved Q/V bf16 pairs
    unsigned int*   Sb   = (unsigned int*)alloc((size_t)N * 64 * 4);
    unsigned short* wt   = (unsigned short*)alloc((size_t)8 * DIM * DIM * 2);
    unsigned short* wtp  = (unsigned short*)alloc((size_t)DIM * 32 * 2);
    // zero region: counts (padded to x4) + 3x stats partials (contiguous, one memset)
    int*   counts = (int*)alloc((size_t)N4 * 16);
    float* stats0 = (float*)alloc(NPART * 256 * 4);
    float* stats1 = (float*)alloc(NPART * 256 * 4);
    float* stats2 = (float*)alloc(NPART * 256 * 4);
    size_t zero_bytes = (size_t)((char*)stats2 + NPART * 256 * 4 - (char*)counts);
    int*   rp     = (int*)alloc((size_t)(N4 * 4 + 1) * 4);
    int*   cursor = (int*)alloc((size_t)N4 * 16);
    int*   bsums  = (int*)alloc(256);
    int*   srcS   = (int*)alloc((size_t)E * 4);

    hipMemsetAsync(counts, 0, zero_bytes, stream);

    // --- CSR by dst (same edges both layers → build once per call)
    hist_kernel<<<(E / 2 + 255) / 256, 256, 0, stream>>>(ei, counts, E);
    int G1 = (N4 + 1023) / 1024;
    scan1_kernel<<<G1, 1024, 0, stream>>>((const int4*)counts, rp, bsums, N4);
    scan3_kernel<<<G1, 1024, 0, stream>>>((const int4*)counts, rp, cursor, bsums, G1, N4, N, E);
    fill_kernel<<<(E / 2 + 255) / 256, 256, 0, stream>>>(ei, cursor, srcS, E);

    // --- weights -> bf16 transposed (+ padded pre_w)
    wconv_kernel<<<9, 128, 0, stream>>>(mp_wk, mp_wq, mp_wv, mp_ws, pre_w, wt, wtp);

    // --- pre layer: MFMA Linear (bf16 out) + fused partial stats
    pre_mfma_kernel<<<(N + PBM - 1) / PBM, 512, 0, stream>>>(
        x, wtp, (unsigned int*)hAb, stats0, N);

    float invN = 1.0f / N;
    int gemm_blocks = (N + GBM - 1) / GBM;

    // --- layer 0
    gemm_fused_kernel<<<gemm_blocks, 512, 0, stream>>>(
        hAb, stats0, pre_g, pre_b, wt, Kb, QVb, Sb, invN, N);
    aggregate_kernel<<<(N + 3) / 4, 256, 0, stream>>>(Kb, QVb, Sb, rp, srcS, hBb, N);
    colstats_kernel<<<1024, 256, 0, stream>>>(hBb, stats1, N);

    // --- layer 1
    gemm_fused_kernel<<<gemm_blocks, 512, 0, stream>>>(
        (const unsigned short*)hBb, stats1, mp_g, mp_b,
        wt + (size_t)4 * DIM * DIM, Kb, QVb, Sb, invN, N);
    aggregate_kernel<<<(N + 3) / 4, 256, 0, stream>>>(Kb, QVb, Sb, rp, srcS, hCb, N);
    colstats_kernel<<<1024, 256, 0, stream>>>(hCb, stats2, N);
    finalize_kernel<<<(N + 3) / 4, 256, 0, stream>>>(
        hCb, (float*)d_out, stats2, mp_g + DIM, mp_b + DIM, invN, N);
}

// Round 13
// 401.016 us; speedup vs baseline: 1.4167x; 1.0284x over previous
//
#include <hip/hip_runtime.h>
#include <math.h>

#define DIM 128
#define DIN 20
#define NPART 32   // stats partials (contention killer)

typedef __attribute__((ext_vector_type(8))) short bf16x8;
typedef __attribute__((ext_vector_type(4))) float f32x4;

__device__ __forceinline__ unsigned short f2bf(float x) {
    unsigned u = __float_as_uint(x);
    u = (u + 0x7FFF + ((u >> 16) & 1)) >> 16;   // RNE
    return (unsigned short)u;
}
__device__ __forceinline__ float sigf(float s) {
    return __builtin_amdgcn_rcpf(1.f + __expf(-s));
}
__device__ __forceinline__ float bflo(unsigned u) { return __uint_as_float(u << 16); }
__device__ __forceinline__ float bfhi(unsigned u) { return __uint_as_float(u & 0xffff0000u); }
__device__ __forceinline__ unsigned packbf(float a, float b) {
    return ((unsigned)f2bf(b) << 16) | f2bf(a);
}
__device__ __forceinline__ float bf2f(short s) {
    return __uint_as_float(((unsigned)(unsigned short)s) << 16);
}

// ---------------------------------------------------------------- CSR build
__global__ void hist_kernel(const int* __restrict__ ei, int* __restrict__ counts, int E) {
    int e = 2 * (blockIdx.x * 256 + threadIdx.x);
    if (e + 1 < E) {
        int2 d = *(const int2*)&ei[E + e];      // row 1 = dst
        atomicAdd(&counts[d.x], 1);
        atomicAdd(&counts[d.y], 1);
    } else if (e < E) {
        atomicAdd(&counts[ei[E + e]], 1);
    }
}

// 4096 elements/block: int4 per thread, register prefix + wave scan + cross-wave LDS.
__global__ __launch_bounds__(1024) void scan1_kernel(const int4* __restrict__ counts4,
                                                     int* __restrict__ incl,
                                                     int* __restrict__ blockSums, int N4) {
    __shared__ int wsum[16];
    int t = threadIdx.x;
    int i4 = blockIdx.x * 1024 + t;
    int4 v = make_int4(0, 0, 0, 0);
    if (i4 < N4) v = counts4[i4];
    int s1 = v.x + v.y, s2 = s1 + v.z, s3 = s2 + v.w;
    int lane = t & 63, w = t >> 6;
    int iw = s3;
    #pragma unroll
    for (int off = 1; off < 64; off <<= 1) {
        int n = __shfl_up(iw, off);
        if (lane >= off) iw += n;
    }
    if (lane == 63) wsum[w] = iw;
    __syncthreads();
    if (t < 16) {
        int x = wsum[t];
        #pragma unroll
        for (int off = 1; off < 16; off <<= 1) {
            int n = __shfl_up(x, off);
            if (t >= off) x += n;
        }
        wsum[t] = x;    // inclusive wave sums
    }
    __syncthreads();
    int base = ((w > 0) ? wsum[w - 1] : 0) + iw - s3;   // exclusive prefix of elem 0
    if (i4 < N4)
        *(int4*)&incl[4 * i4] = make_int4(base + v.x, base + s1, base + s2, base + s3);
    if (t == 0) blockSums[blockIdx.x] = wsum[15];
}

// incl -> exclusive (in place) + cursor copy; block offset recomputed from blockSums.
__global__ __launch_bounds__(1024) void scan3_kernel(const int4* __restrict__ counts4,
                                                     int* __restrict__ rp,
                                                     int* __restrict__ cursor,
                                                     const int* __restrict__ blockSums,
                                                     int G, int N4, int N, int E) {
    __shared__ int boff_s;
    int t = threadIdx.x;
    if (t < 64) {
        int v = (t < G && t < (int)blockIdx.x) ? blockSums[t] : 0;
        #pragma unroll
        for (int off = 32; off; off >>= 1) v += __shfl_xor(v, off);
        if (t == 0) boff_s = v;
    }
    __syncthreads();
    int i4 = blockIdx.x * 1024 + t;
    if (i4 < N4) {
        int4 c = counts4[i4];
        int4 inc = *(const int4*)&rp[4 * i4];
        int b = boff_s;
        int4 ex = make_int4(inc.x - c.x + b, inc.y - c.y + b, inc.z - c.z + b, inc.w - c.w + b);
        *(int4*)&rp[4 * i4] = ex;
        *(int4*)&cursor[4 * i4] = ex;
    }
    if (i4 == 0) rp[N] = E;
}

__global__ void fill_kernel(const int* __restrict__ ei, int* __restrict__ cursor,
                            int* __restrict__ srcS, int E) {
    int e = 2 * (blockIdx.x * 256 + threadIdx.x);
    if (e + 1 < E) {
        int2 s = *(const int2*)&ei[e];           // row 0 = src
        int2 d = *(const int2*)&ei[E + e];       // row 1 = dst
        int p0 = atomicAdd(&cursor[d.x], 1);
        srcS[p0] = s.x;
        int p1 = atomicAdd(&cursor[d.y], 1);
        srcS[p1] = s.y;
    } else if (e < E) {
        int d = ei[E + e];
        int pos = atomicAdd(&cursor[d], 1);
        srcS[pos] = ei[e];
    }
}

// ---------------------------------------------------------------- weight convert (LDS transpose)
// blocks 0-7: layer weights W[k][c] f32 -> Wt[c][k] bf16 [128][128], both phases coalesced.
// block  8  : pre_w [20][128] -> Wtp[c][k] bf16 [128][32], k>=20 zero-padded.
__global__ __launch_bounds__(256) void wconv_kernel(const float* __restrict__ wk,
                                                    const float* __restrict__ wq,
                                                    const float* __restrict__ wv,
                                                    const float* __restrict__ ws,
                                                    const float* __restrict__ pw,
                                                    unsigned short* __restrict__ wt,
                                                    unsigned short* __restrict__ wtp) {
    int b = blockIdx.x;
    int tid = threadIdx.x;
    if (b < 8) {
        __shared__ unsigned short tile[128][130];   // +2 pad: stride 260B -> bank+1
        int l = b >> 2, w = b & 3;
        const float* src = (w == 0 ? wk : w == 1 ? wq : w == 2 ? wv : ws) + (size_t)l * DIM * DIM;
        unsigned short* dst = wt + (size_t)b * DIM * DIM;
        int c = tid & 127;
        #pragma unroll
        for (int i = 0; i < 64; ++i) {
            int k = i * 2 + (tid >> 7);
            tile[k][c] = f2bf(src[k * DIM + c]);    // coalesced read
        }
        __syncthreads();
        int k2 = tid & 127;
        #pragma unroll
        for (int i = 0; i < 64; ++i) {
            int c2 = i * 2 + (tid >> 7);
            dst[c2 * DIM + k2] = tile[k2][c2];      // coalesced write
        }
    } else if (tid < 128) {
        for (int k = 0; k < 32; ++k)
            wtp[tid * 32 + k] = (k < DIN) ? f2bf(pw[k * DIM + tid]) : (unsigned short)0;
    }
}

// ---------------------------------------------------------------- BN prep: partials -> scale|shift (1 block)
__global__ void bnprep_kernel(const float* __restrict__ part,
                              const float* __restrict__ gamma, const float* __restrict__ beta,
                              float* __restrict__ scsh, float invN) {
    int c = threadIdx.x;     // 128
    float s = 0.f, q = 0.f;
    #pragma unroll 8
    for (int p = 0; p < NPART; ++p) {
        s += part[p * 256 + c];
        q += part[p * 256 + 128 + c];
    }
    float mu = s * invN;
    float var = q * invN - mu * mu;
    float sc = gamma[c] * rsqrtf(var + 1e-5f);
    scsh[c] = sc;
    scsh[128 + c] = beta[c] - mu * sc;
}

// ---------------------------------------------------------------- pre GEMM via MFMA (K=20 padded to 32)
#define PBM 64
__global__ __launch_bounds__(512) void pre_mfma_kernel(
        const float* __restrict__ x,             // [N][20]
        const unsigned short* __restrict__ Wp,   // [128][32] bf16 (col-major k, padded)
        unsigned int* __restrict__ hb,           // [N][64] bf16 pairs
        float* __restrict__ stats, int N) {      // [32][256] partials
    __shared__ float xs[PBM * DIN];              // 5 KB raw f32 tile
    __shared__ unsigned short Asw[PBM * 32];     // 4 KB bf16, swizzled
    int tid = threadIdx.x;
    int row0 = blockIdx.x * PBM;
    int base = row0 * DIN;
    int total = N * DIN;

    if (tid < 320) {                             // 64 rows x 20 f32 = 320 float4, coalesced
        float4 v = make_float4(0.f, 0.f, 0.f, 0.f);
        int gi = base + tid * 4;
        if (gi + 3 < total) {
            v = *(const float4*)(x + gi);
        } else {
            float* vp = (float*)&v;
            #pragma unroll
            for (int j = 0; j < 4; ++j) if (gi + j < total) vp[j] = x[gi + j];
        }
        *(float4*)&xs[tid * 4] = v;
    }
    __syncthreads();

    {   // convert: thread t -> row = t>>3, k4 = (t&7)*4 (zeros for k>=20)
        int r = tid >> 3, k4 = (tid & 7) * 4;
        float v0 = 0.f, v1 = 0.f, v2 = 0.f, v3 = 0.f;
        if (k4 < DIN) {
            float4 f = *(const float4*)&xs[r * DIN + k4];
            v0 = f.x; v1 = f.y; v2 = f.z; v3 = f.w;
        }
        int byteoff = r * 64 + ((k4 * 2) ^ ((r & 3) << 4));
        *(uint2*)((char*)Asw + byteoff) = make_uint2(packbf(v0, v1), packbf(v2, v3));
    }
    __syncthreads();

    int w = tid >> 6, l = tid & 63;
    int c0 = w * 16;
    int lj = l & 15, lg = l >> 4;

    bf16x8 wf = *(const bf16x8*)(Wp + (size_t)(c0 + lj) * 32 + lg * 8);
    f32x4 acc[4];
    #pragma unroll
    for (int mf = 0; mf < 4; ++mf) {
        int r = mf * 16 + lj;
        int off = r * 64 + ((lg * 16) ^ ((r & 3) << 4));
        bf16x8 act = *(const bf16x8*)((char*)Asw + off);
        f32x4 z = {0.f, 0.f, 0.f, 0.f};
        acc[mf] = __builtin_amdgcn_mfma_f32_16x16x32_bf16(wf, act, z, 0, 0, 0);
    }

    // epilogue: lane holds row = row0+mf*16+lj, cols = c0+lg*4+(0..3)
    float s[4] = {}, q[4] = {};
    #pragma unroll
    for (int mf = 0; mf < 4; ++mf) {
        int row = row0 + mf * 16 + lj;
        f32x4 v = acc[mf];
        #pragma unroll
        for (int j = 0; j < 4; ++j) {
            s[j] += v[j];
            q[j] = fmaf(v[j], v[j], q[j]);
        }
        if (row < N) {
            int pidx = (c0 >> 1) + lg * 2;
            *(uint2*)(hb + (size_t)row * 64 + pidx) =
                make_uint2(packbf(v[0], v[1]), packbf(v[2], v[3]));
        }
    }
    #pragma unroll
    for (int off = 1; off < 16; off <<= 1) {     // reduce over lj (16-lane groups)
        #pragma unroll
        for (int j = 0; j < 4; ++j) {
            s[j] += __shfl_xor(s[j], off);
            q[j] += __shfl_xor(q[j], off);
        }
    }
    if (lj == 0) {
        float* sp = stats + (blockIdx.x & (NPART - 1)) * 256;
        int c = c0 + lg * 4;
        #pragma unroll
        for (int j = 0; j < 4; ++j) {
            atomicAdd(&sp[c + j], s[j]);
            atomicAdd(&sp[128 + c + j], q[j]);
        }
    }
}

// ---------------------------------------------------------------- fused MFMA GEMM: BN+ReLU+L2norm in staging
#define GBM 64
__global__ __launch_bounds__(512) void gemm_fused_kernel(
        const unsigned short* __restrict__ hb,   // [N][128] bf16 (raw, pre-BN)
        const float* __restrict__ scsh,          // [256] scale | shift
        const unsigned short* __restrict__ Wt,   // [4][128][128] bf16 (col-major k)
        unsigned int* __restrict__ Kb,           // [N][64] bf16 pairs
        unsigned int* __restrict__ QV,           // [N][128] interleaved Q/V bf16 pairs
        unsigned int* __restrict__ Sb,           // [N][64] bf16 pairs
        int N) {
    __shared__ unsigned short Asw[GBM * DIM];    // 16 KB, swizzled
    __shared__ float sc_s[DIM], sh_s[DIM];
    int tid = threadIdx.x;
    if (tid < DIM) {
        sc_s[tid] = scsh[tid];
        sh_s[tid] = scsh[128 + tid];
    }
    __syncthreads();
    int row0 = blockIdx.x * GBM;

    #pragma unroll
    for (int i = 0; i < 2; ++i) {
        int g = tid + i * 512;                   // 0..1023
        int r = g >> 4, ch = g & 15;             // row 0..63, 16 lanes per row
        int row = row0 + r;
        int cb = ch * 8;
        float y[8];
        if (row < N) {
            bf16x8 hv = *(const bf16x8*)(hb + (size_t)row * DIM + cb);
            #pragma unroll
            for (int j = 0; j < 8; ++j)
                y[j] = fmaxf(fmaf(bf2f(hv[j]), sc_s[cb + j], sh_s[cb + j]), 0.f);
        } else {
            #pragma unroll
            for (int j = 0; j < 8; ++j) y[j] = 0.f;
        }
        float ss = 0.f;
        #pragma unroll
        for (int j = 0; j < 8; ++j) ss = fmaf(y[j], y[j], ss);
        #pragma unroll
        for (int off = 1; off < 16; off <<= 1) ss += __shfl_xor(ss, off);
        float inv = 1.0f / fmaxf(sqrtf(ss), 1e-12f);
        bf16x8 o;
        #pragma unroll
        for (int j = 0; j < 8; ++j) o[j] = (short)f2bf(y[j] * inv);
        int dst = r * 256 + ((ch * 16) ^ ((r & 7) << 4));
        *(bf16x8*)((char*)Asw + dst) = o;
    }
    __syncthreads();

    int w = tid >> 6, l = tid & 63;
    int c0 = w * 16;
    int lj = l & 15, lg = l >> 4;

    bf16x8 act[4][4];
    #pragma unroll
    for (int mf = 0; mf < 4; ++mf) {
        int r = mf * 16 + lj;
        #pragma unroll
        for (int ks = 0; ks < 4; ++ks) {
            int off = r * 256 + ((ks * 64 + lg * 16) ^ ((r & 7) << 4));
            act[mf][ks] = *(const bf16x8*)((char*)Asw + off);
        }
    }

    #pragma unroll
    for (int wgt = 0; wgt < 4; ++wgt) {          // 0:K 1:Q 2:V 3:S
        const unsigned short* W = Wt + (size_t)wgt * DIM * DIM;
        bf16x8 wf[4];
        #pragma unroll
        for (int ks = 0; ks < 4; ++ks)
            wf[ks] = *(const bf16x8*)(W + (size_t)(c0 + lj) * DIM + ks * 32 + lg * 8);
        f32x4 acc[4] = {};
        #pragma unroll
        for (int mf = 0; mf < 4; ++mf)
            #pragma unroll
            for (int ks = 0; ks < 4; ++ks)
                acc[mf] = __builtin_amdgcn_mfma_f32_16x16x32_bf16(
                    wf[ks], act[mf][ks], acc[mf], 0, 0, 0);
        // lane holds: row = row0 + mf*16 + lj ; cols = c0 + lg*4 + (0..3)
        #pragma unroll
        for (int mf = 0; mf < 4; ++mf) {
            int row = row0 + mf * 16 + lj;
            if (row < N) {
                int col = c0 + lg * 4;
                f32x4 v = acc[mf];
                unsigned p0 = packbf(v[0], v[1]);
                unsigned p1 = packbf(v[2], v[3]);
                if (wgt == 0) {
                    *(uint2*)(Kb + (size_t)row * 64 + (col >> 1)) = make_uint2(p0, p1);
                } else if (wgt == 3) {
                    *(uint2*)(Sb + (size_t)row * 64 + (col >> 1)) = make_uint2(p0, p1);
                } else {
                    unsigned* U = QV + (size_t)row * 128;
                    if (wgt == 1) { U[col]     = p0; U[col + 2] = p1; }
                    else          { U[col + 1] = p0; U[col + 3] = p1; }
                }
            }
        }
    }
}

// ---------------------------------------------------------------- pull aggregation (CSR by dst), bf16 out
__global__ __launch_bounds__(256) void aggregate_kernel(
        const unsigned int* __restrict__ Kb, const unsigned int* __restrict__ QV,
        const unsigned int* __restrict__ Sb,
        const int* __restrict__ rp, const int* __restrict__ srcS,
        unsigned int* __restrict__ outb, int N) {
    int node = blockIdx.x * 4 + (threadIdx.x >> 6);
    if (node >= N) return;
    int l = threadIdx.x & 63;
    int sub = l & 31;
    int half = l >> 5;
    uint2 kp = *(const uint2*)(Kb + (size_t)node * 64 + 2 * sub);
    float k0 = bflo(kp.x), k1 = bfhi(kp.x), k2 = bflo(kp.y), k3 = bfhi(kp.y);
    int beg = rp[node], end = rp[node + 1];
    int cnt = end - beg;
    int npairs = cnt >> 1;
    float a0 = 0, a1 = 0, a2 = 0, a3 = 0;
    int p = 0;
    for (; p + 4 <= npairs; p += 4) {            // 8 edges/iter (4 per half)
        int e = beg + 2 * p + half;
        int j0 = srcS[e];
        int j1 = srcS[e + 2];
        int j2 = srcS[e + 4];
        int j3 = srcS[e + 6];
        uint4 u0 = *(const uint4*)(QV + (size_t)j0 * 128 + 4 * sub);
        uint4 u1 = *(const uint4*)(QV + (size_t)j1 * 128 + 4 * sub);
        uint4 u2 = *(const uint4*)(QV + (size_t)j2 * 128 + 4 * sub);
        uint4 u3 = *(const uint4*)(QV + (size_t)j3 * 128 + 4 * sub);
        a0 = fmaf(sigf(k0 + bflo(u0.x)), bflo(u0.y), a0);
        a1 = fmaf(sigf(k1 + bfhi(u0.x)), bfhi(u0.y), a1);
        a2 = fmaf(sigf(k2 + bflo(u0.z)), bflo(u0.w), a2);
        a3 = fmaf(sigf(k3 + bfhi(u0.z)), bfhi(u0.w), a3);
        a0 = fmaf(sigf(k0 + bflo(u1.x)), bflo(u1.y), a0);
        a1 = fmaf(sigf(k1 + bfhi(u1.x)), bfhi(u1.y), a1);
        a2 = fmaf(sigf(k2 + bflo(u1.z)), bflo(u1.w), a2);
        a3 = fmaf(sigf(k3 + bfhi(u1.z)), bfhi(u1.w), a3);
        a0 = fmaf(sigf(k0 + bflo(u2.x)), bflo(u2.y), a0);
        a1 = fmaf(sigf(k1 + bfhi(u2.x)), bfhi(u2.y), a1);
        a2 = fmaf(sigf(k2 + bflo(u2.z)), bflo(u2.w), a2);
        a3 = fmaf(sigf(k3 + bfhi(u2.z)), bfhi(u2.w), a3);
        a0 = fmaf(sigf(k0 + bflo(u3.x)), bflo(u3.y), a0);
        a1 = fmaf(sigf(k1 + bfhi(u3.x)), bfhi(u3.y), a1);
        a2 = fmaf(sigf(k2 + bflo(u3.z)), bflo(u3.w), a2);
        a3 = fmaf(sigf(k3 + bfhi(u3.z)), bfhi(u3.w), a3);
    }
    for (; p < npairs; ++p) {
        int e = beg + 2 * p + half;
        int j = srcS[e];
        uint4 u = *(const uint4*)(QV + (size_t)j * 128 + 4 * sub);
        a0 = fmaf(sigf(k0 + bflo(u.x)), bflo(u.y), a0);
        a1 = fmaf(sigf(k1 + bfhi(u.x)), bfhi(u.y), a1);
        a2 = fmaf(sigf(k2 + bflo(u.z)), bflo(u.w), a2);
        a3 = fmaf(sigf(k3 + bfhi(u.z)), bfhi(u.w), a3);
    }
    if ((cnt & 1) && half == 0) {                // leftover edge -> half 0
        int j = srcS[beg + cnt - 1];
        uint4 u = *(const uint4*)(QV + (size_t)j * 128 + 4 * sub);
        a0 = fmaf(sigf(k0 + bflo(u.x)), bflo(u.y), a0);
        a1 = fmaf(sigf(k1 + bfhi(u.x)), bfhi(u.y), a1);
        a2 = fmaf(sigf(k2 + bflo(u.z)), bflo(u.w), a2);
        a3 = fmaf(sigf(k3 + bfhi(u.z)), bfhi(u.w), a3);
    }
    a0 += __shfl_xor(a0, 32);
    a1 += __shfl_xor(a1, 32);
    a2 += __shfl_xor(a2, 32);
    a3 += __shfl_xor(a3, 32);
    if (half == 0) {
        uint2 sp = *(const uint2*)(Sb + (size_t)node * 64 + 2 * sub);
        float o0 = a0 + bflo(sp.x);
        float o1 = a1 + bfhi(sp.x);
        float o2 = a2 + bflo(sp.y);
        float o3 = a3 + bfhi(sp.y);
        *(uint2*)(outb + (size_t)node * 64 + 2 * sub) =
            make_uint2(packbf(o0, o1), packbf(o2, o3));
    }
}

// ---------------------------------------------------------------- BN column stats over bf16 pairs [N][64]
// 256 thr = 4 row-group waves; LDS reduce; atomics into 32-way partials.
__global__ __launch_bounds__(256) void colstats_kernel(const unsigned int* __restrict__ hb,
                                                       float* __restrict__ stats, int N) {
    __shared__ float red[1024];
    int tid = threadIdx.x;
    int c = tid & 63;
    int g = tid >> 6;
    float s0 = 0.f, s1 = 0.f, q0 = 0.f, q1 = 0.f;
    for (int r = blockIdx.x * 4 + g; r < N; r += gridDim.x * 4) {
        unsigned p = hb[(size_t)r * 64 + c];
        float a = bflo(p), b = bfhi(p);
        s0 += a; q0 = fmaf(a, a, q0);
        s1 += b; q1 = fmaf(b, b, q1);
    }
    red[tid] = s0; red[256 + tid] = s1; red[512 + tid] = q0; red[768 + tid] = q1;
    __syncthreads();
    if (tid < 64) {
        float* sp = stats + (blockIdx.x & (NPART - 1)) * 256;
        float S0 = red[c] + red[c + 64] + red[c + 128] + red[c + 192];
        float S1 = red[256 + c] + red[256 + c + 64] + red[256 + c + 128] + red[256 + c + 192];
        float Q0 = red[512 + c] + red[512 + c + 64] + red[512 + c + 128] + red[512 + c + 192];
        float Q1 = red[768 + c] + red[768 + c + 64] + red[768 + c + 128] + red[768 + c + 192];
        atomicAdd(&sp[2 * c], S0);
        atomicAdd(&sp[2 * c + 1], S1);
        atomicAdd(&sp[128 + 2 * c], Q0);
        atomicAdd(&sp[128 + 2 * c + 1], Q1);
    }
}

// ---------------------------------------------------------------- final BN + ReLU + L2 norm: bf16 in -> f32 out
__global__ __launch_bounds__(512) void finalize_kernel(
        const unsigned int* __restrict__ hb, float* __restrict__ out,
        const float* __restrict__ scsh, int N) {
    __shared__ float sc_s[DIM], sh_s[DIM];
    int tid = threadIdx.x;
    if (tid < DIM) {
        sc_s[tid] = scsh[tid];
        sh_s[tid] = scsh[128 + tid];
    }
    __syncthreads();
    int row = blockIdx.x * 8 + (tid >> 6);
    int lane = tid & 63;
    if (row >= N) return;
    unsigned p = hb[(size_t)row * 64 + lane];   // cols 2*lane, 2*lane+1
    int c0 = 2 * lane, c1 = 2 * lane + 1;
    float y0 = fmaxf(fmaf(bflo(p), sc_s[c0], sh_s[c0]), 0.f);
    float y1 = fmaxf(fmaf(bfhi(p), sc_s[c1], sh_s[c1]), 0.f);
    float ss = y0 * y0 + y1 * y1;
    #pragma unroll
    for (int off = 32; off; off >>= 1) ss += __shfl_xor(ss, off);
    float inv = 1.0f / fmaxf(sqrtf(ss), 1e-12f);
    *(float2*)(out + (size_t)row * DIM + c0) = make_float2(y0 * inv, y1 * inv);
}

// ---------------------------------------------------------------- launch
extern "C" void kernel_launch(void* const* d_in, const int* in_sizes, int n_in,
                              void* d_out, int out_size, void* d_ws, size_t ws_size,
                              hipStream_t stream) {
    const float* x     = (const float*)d_in[0];
    const int*   ei    = (const int*)d_in[1];
    const float* pre_w = (const float*)d_in[2];
    const float* pre_g = (const float*)d_in[3];
    const float* pre_b = (const float*)d_in[4];
    const float* mp_wk = (const float*)d_in[5];
    const float* mp_wq = (const float*)d_in[6];
    const float* mp_wv = (const float*)d_in[7];
    const float* mp_ws = (const float*)d_in[8];
    const float* mp_g  = (const float*)d_in[9];
    const float* mp_b  = (const float*)d_in[10];
    const int N = in_sizes[0] / DIN;     // 50000
    const int E = in_sizes[1] / 2;       // 800000
    const int N4 = (N + 3) / 4;

    char* wsp = (char*)d_ws;
    size_t off = 0;
    auto alloc = [&](size_t bytes) {
        void* p = wsp + off;
        off = (off + bytes + 255) & ~(size_t)255;
        return p;
    };
    unsigned short* hAb  = (unsigned short*)alloc((size_t)N * DIM * 2);  // raw pre-GEMM out
    unsigned int*   hBb  = (unsigned int*)alloc((size_t)N * 64 * 4);     // agg out l0 (bf16 pairs)
    unsigned int*   hCb  = (unsigned int*)alloc((size_t)N * 64 * 4);     // agg out l1 (bf16 pairs)
    unsigned int*   Kb   = (unsigned int*)alloc((size_t)N * 64 * 4);
    unsigned int*   QVb  = (unsigned int*)alloc((size_t)N * 128 * 4);    // interleaved Q/V bf16 pairs
    unsigned int*   Sb   = (unsigned int*)alloc((size_t)N * 64 * 4);
    unsigned short* wt   = (unsigned short*)alloc((size_t)8 * DIM * DIM * 2);
    unsigned short* wtp  = (unsigned short*)alloc((size_t)DIM * 32 * 2);
    // zero region: counts (padded to x4) + 3x stats partials (contiguous, one memset)
    int*   counts = (int*)alloc((size_t)N4 * 16);
    float* stats0 = (float*)alloc(NPART * 256 * 4);
    float* stats1 = (float*)alloc(NPART * 256 * 4);
    float* stats2 = (float*)alloc(NPART * 256 * 4);
    size_t zero_bytes = (size_t)((char*)stats2 + NPART * 256 * 4 - (char*)counts);
    float* scsh0  = (float*)alloc(256 * 4);
    float* scsh1  = (float*)alloc(256 * 4);
    float* scsh2  = (float*)alloc(256 * 4);
    int*   rp     = (int*)alloc((size_t)(N4 * 4 + 1) * 4);
    int*   cursor = (int*)alloc((size_t)N4 * 16);
    int*   bsums  = (int*)alloc(256);
    int*   srcS   = (int*)alloc((size_t)E * 4);

    hipMemsetAsync(counts, 0, zero_bytes, stream);

    // --- CSR by dst (same edges both layers → build once per call)
    hist_kernel<<<(E / 2 + 255) / 256, 256, 0, stream>>>(ei, counts, E);
    int G1 = (N4 + 1023) / 1024;
    scan1_kernel<<<G1, 1024, 0, stream>>>((const int4*)counts, rp, bsums, N4);
    scan3_kernel<<<G1, 1024, 0, stream>>>((const int4*)counts, rp, cursor, bsums, G1, N4, N, E);
    fill_kernel<<<(E / 2 + 255) / 256, 256, 0, stream>>>(ei, cursor, srcS, E);

    // --- weights -> bf16 transposed (+ padded pre_w)
    wconv_kernel<<<9, 256, 0, stream>>>(mp_wk, mp_wq, mp_wv, mp_ws, pre_w, wt, wtp);

    // --- pre layer: MFMA Linear (bf16 out) + fused partial stats
    pre_mfma_kernel<<<(N + PBM - 1) / PBM, 512, 0, stream>>>(
        x, wtp, (unsigned int*)hAb, stats0, N);

    float invN = 1.0f / N;
    int gemm_blocks = (N + GBM - 1) / GBM;

    // --- layer 0
    bnprep_kernel<<<1, 128, 0, stream>>>(stats0, pre_g, pre_b, scsh0, invN);
    gemm_fused_kernel<<<gemm_blocks, 512, 0, stream>>>(
        hAb, scsh0, wt, Kb, QVb, Sb, N);
    aggregate_kernel<<<(N + 3) / 4, 256, 0, stream>>>(Kb, QVb, Sb, rp, srcS, hBb, N);
    colstats_kernel<<<1024, 256, 0, stream>>>(hBb, stats1, N);

    // --- layer 1
    bnprep_kernel<<<1, 128, 0, stream>>>(stats1, mp_g, mp_b, scsh1, invN);
    gemm_fused_kernel<<<gemm_blocks, 512, 0, stream>>>(
        (const unsigned short*)hBb, scsh1, wt + (size_t)4 * DIM * DIM, Kb, QVb, Sb, N);
    aggregate_kernel<<<(N + 3) / 4, 256, 0, stream>>>(Kb, QVb, Sb, rp, srcS, hCb, N);
    colstats_kernel<<<1024, 256, 0, stream>>>(hCb, stats2, N);
    bnprep_kernel<<<1, 128, 0, stream>>>(stats2, mp_g + DIM, mp_b + DIM, scsh2, invN);
    finalize_kernel<<<(N + 7) / 8, 512, 0, stream>>>(hCb, (float*)d_out, scsh2, N);
}